// Round 14
// baseline (215.721 us; speedup 1.0000x reference)
//
#include <hip/hip_runtime.h>
#include <hip/hip_bf16.h>

#define DD 256
#define SCALAR 30.0f
#define K2 43.28085122666891f     // 30 * log2(e)
#define LN2 0.6931471805599453f
#define NT 16                     // 32-col fp32 subtiles per block; 4688 = 293*16

typedef __attribute__((ext_vector_type(8))) short bf16x8;
typedef __attribute__((ext_vector_type(4))) float f32x4;

__device__ __forceinline__ float fexp2(float x) {
#if __has_builtin(__builtin_amdgcn_exp2f)
    return __builtin_amdgcn_exp2f(x);
#else
    return exp2f(x);
#endif
}

// RNE float->bf16 via HW cvt (compiler emits v_cvt_pk_bf16_f32 for pairs)
__device__ __forceinline__ unsigned short f2b(float f) {
    __hip_bfloat16 h = __float2bfloat16(f);
    return __builtin_bit_cast(unsigned short, h);
}

__device__ __forceinline__ bf16x8 cvt8(f32x4 a, f32x4 b) {
    bf16x8 r;
    r[0] = (short)f2b(a[0]); r[1] = (short)f2b(a[1]);
    r[2] = (short)f2b(a[2]); r[3] = (short)f2b(a[3]);
    r[4] = (short)f2b(b[0]); r[5] = (short)f2b(b[1]);
    r[6] = (short)f2b(b[2]); r[7] = (short)f2b(b[3]);
    return r;
}

// async global->LDS; dest = wave-uniform base + lane*width
__device__ __forceinline__ void gload16(const void* g, void* l) {
    __builtin_amdgcn_global_load_lds((const __attribute__((address_space(1))) void*)g,
                                     (__attribute__((address_space(3))) void*)l, 16, 0, 0);
}
__device__ __forceinline__ void gload4(const void* g, void* l) {
    __builtin_amdgcn_global_load_lds((const __attribute__((address_space(1))) void*)g,
                                     (__attribute__((address_space(3))) void*)l, 4, 0, 0);
}

// K0: x = l2norm(inputs); fp32 + bf16 copies; zero loss accumulator.
__global__ void prep_kernel(const float* __restrict__ in, float* __restrict__ xf,
                            unsigned short* __restrict__ xb, float* __restrict__ out_loss) {
    int row = blockIdx.x, tid = threadIdx.x;
    __shared__ float red[256];
    float v = in[(size_t)row * DD + tid];
    red[tid] = v * v;
    __syncthreads();
    for (int h = 128; h > 0; h >>= 1) {
        if (tid < h) red[tid] += red[tid + h];
        __syncthreads();
    }
    float nrm = fmaxf(sqrtf(red[0]), 1e-12f);
    float xn = v / nrm;
    xf[(size_t)row * DD + tid] = xn;
    xb[(size_t)row * DD + tid] = f2b(xn);
    if (row == 0 && tid == 0) out_loss[0] = 0.f;
}

// K1: GEMM + lse partials + fused out-copy. Touches lut/cq fp32 EXACTLY ONCE.
// grid (4 rb, 293 bx): rb-quad of one bx dispatch-adjacent -> B panel L2/L3-hot.
// Per block: 16 subtiles of 32 cols staged fp32 in LDS (swizzled slots,
// pre-swizzled gload src); bf16 conversion in-register per MFMA fragment;
// each rb writes 1/4 of the shifted out-copy from LDS (nt stores).
// Subtile boundary float via 1-lane gload4 side-slot (keeps counted vmcnt).
__global__ __launch_bounds__(256, 2) void gemm_lse_copy_kernel(
    const unsigned short* __restrict__ xb, const float* __restrict__ lut,
    const float* __restrict__ cq, float* __restrict__ dout,
    float* __restrict__ pm, float* __restrict__ ps,
    int N, long PD, long TOT, int GB) {
    __shared__ float Fs[2][8192];      // 2 x 32KB fp32 subtile, 16B slots s hold linear slot s^((s>>6)&7)
    __shared__ float bside[2];         // flat[s0-1] per buffered subtile
    int tid = threadIdx.x;
    int w = tid >> 6, lane = tid & 63;
    int l15 = lane & 15, lg = lane >> 4;
    int rb = blockIdx.x, bx = blockIdx.y;
    int row0 = rb * 256 + w * 64;

    // A -> registers FIRST (oldest vmem ops): 4 rf x 8 kc x 16B = 128 VGPR
    bf16x8 areg[4][8];
    const char* ab = (const char*)xb + ((size_t)(row0 + l15) * 256 + lg * 8) * 2;
    #pragma unroll
    for (int rf = 0; rf < 4; ++rf)
        #pragma unroll
        for (int kc = 0; kc < 8; ++kc)
            areg[rf][kc] = *(const bf16x8*)(ab + rf * (16 * 512) + kc * 64);

    long sb0 = (long)bx * NT * 8192;   // flat float base of this block's subtiles

    auto side_load = [&](int t) {      // 1-lane DMA of flat[s0-1] -> bside[t&1]
        long s0 = sb0 + (long)t * 8192;
        if (rb == 0 && w == 0 && lane == 0 && s0 > 0) {
            long f = s0 - 1;
            const float* sp = (f < PD) ? (lut + f) : (cq + (f - PD));
            gload4(sp, &bside[t & 1]);
        }
    };
    auto stage = [&](int t, int b) {   // 8 x gload16 per thread-wave-round
        long sbase = sb0 + (long)t * 8192;
        const float* sbp = (sbase < PD) ? (lut + sbase) : (cq + (sbase - PD));
        #pragma unroll
        for (int r = 0; r < 8; ++r) {
            int s = r * 256 + w * 64 + lane;
            long off = 4L * (long)(s ^ ((s >> 6) & 7));   // pre-swizzled source
            if (sbase + off >= TOT) off = 0;              // phantom clamp (last subtile only)
            gload16(sbp + off, &Fs[b][(size_t)(r * 256 + w * 64) * 4]);
        }
    };

    side_load(0); stage(0, 0);
    side_load(1); stage(1, 1);

    float rm[4], rs[4];
    #pragma unroll
    for (int rf = 0; rf < 4; ++rf) { rm[rf] = -1e30f; rs[rf] = 0.f; }

    #pragma unroll 1
    for (int t = 0; t < NT; ++t) {
        if (t < NT - 1) asm volatile("s_waitcnt vmcnt(8)" ::: "memory");
        else            asm volatile("s_waitcnt vmcnt(0)" ::: "memory");
        __builtin_amdgcn_s_barrier();
        int b = t & 1;

        // ---- out-copy: this rb's quarter of the subtile (512 chunks of 16B) ----
        {
            long s0 = sb0 + (long)t * 8192;
            long mg0 = s0 >> 2;
            #pragma unroll
            for (int h = 0; h < 2; ++h) {
                int j = rb * 512 + h * 256 + tid;     // local chunk in [0,2048)
                long m = mg0 + j;
                if (4 * m + 3 > TOT) continue;        // phantom / end guard
                float v0, v1, v2, v3;
                if (j == 0) {
                    if (m == 0) {                      // very first chunk: dout[1..3]
                        int u0 = 0 ^ 0;                // slots 0..0 col 0: swizzle identity
                        dout[1] = Fs[b][0]; dout[2] = Fs[b][1]; dout[3] = Fs[b][2];
                        continue;
                    }
                    v0 = bside[b];
                } else {
                    int f = 4 * j - 1;
                    int sl = (f >> 2) ^ ((f >> 8) & 7);
                    v0 = Fs[b][sl * 4 + (f & 3)];
                }
                int f1 = 4 * j;
                int sl1 = (f1 >> 2) ^ ((f1 >> 8) & 7);
                v1 = Fs[b][sl1 * 4 + 0];
                v2 = Fs[b][sl1 * 4 + 1];
                v3 = Fs[b][sl1 * 4 + 2];
                f32x4 o = (f32x4){v0, v1, v2, v3};
                __builtin_nontemporal_store(o, (f32x4*)(dout + 4 * m));
            }
            // last valid element dout[TOT] = flat[TOT-1]
            if (bx == GB - 1 && t == NT - 1 && rb == 0 && tid == 0) {
                int f = (int)(TOT - 1 - s0);
                int sl = (f >> 2) ^ ((f >> 8) & 7);
                dout[TOT] = Fs[b][sl * 4 + (f & 3)];
            }
        }

        // ---- MFMA: fragments converted fp32->bf16 in-register ----
        f32x4 acc[2][4];   // [cf][rf]
        #pragma unroll
        for (int cf = 0; cf < 2; ++cf)
            #pragma unroll
            for (int rf = 0; rf < 4; ++rf) acc[cf][rf] = (f32x4){0.f, 0.f, 0.f, 0.f};

        #pragma unroll
        for (int k0 = 0; k0 < 8; ++k0) {
            bf16x8 bb[2];
            #pragma unroll
            for (int cf = 0; cf < 2; ++cf) {
                int col = cf * 16 + l15;
                int slot = col * 64 + k0 * 8 + lg * 2;
                int k7 = col & 7;
                f32x4 fa = *(const f32x4*)&Fs[b][(size_t)(slot ^ k7) * 4];
                f32x4 fb = *(const f32x4*)&Fs[b][(size_t)((slot + 1) ^ k7) * 4];
                bb[cf] = cvt8(fa, fb);
            }
            #pragma unroll
            for (int rf = 0; rf < 4; ++rf)
                #pragma unroll
                for (int cf = 0; cf < 2; ++cf)
                    acc[cf][rf] = __builtin_amdgcn_mfma_f32_16x16x32_bf16(bb[cf], areg[rf][k0], acc[cf][rf], 0, 0, 0);
        }

        asm volatile("s_waitcnt lgkmcnt(0)" ::: "memory");
        __builtin_amdgcn_s_barrier();
        if (t + 2 < NT) { side_load(t + 2); stage(t + 2, b); }

        // ---- fold (register-only, under the DMA flight) ----
        bool lastT = (bx == GB - 1) && (t == NT - 1);   // cols 150000..150015 phantom -> skip cf1
        #pragma unroll
        for (int rf = 0; rf < 4; ++rf) {
            float lmraw = acc[0][rf][0];
            #pragma unroll
            for (int r = 1; r < 4; ++r) lmraw = fmaxf(lmraw, acc[0][rf][r]);
            if (!lastT) {
                #pragma unroll
                for (int r = 0; r < 4; ++r) lmraw = fmaxf(lmraw, acc[1][rf][r]);
            }
            float lm = fmaxf(rm[rf], K2 * lmraw);
            float ls = rs[rf] * fexp2(rm[rf] - lm);
            #pragma unroll
            for (int r = 0; r < 4; ++r) ls += fexp2(fmaf(K2, acc[0][rf][r], -lm));
            if (!lastT) {
                #pragma unroll
                for (int r = 0; r < 4; ++r) ls += fexp2(fmaf(K2, acc[1][rf][r], -lm));
            }
            rm[rf] = lm; rs[rf] = ls;
        }
    }

    // cross-lane-group merge (copies at lanes l15+16k)
    #pragma unroll
    for (int rf = 0; rf < 4; ++rf) {
        float m = rm[rf], s = rs[rf];
        float m1 = __shfl_xor(m, 16), s1 = __shfl_xor(s, 16);
        float M = fmaxf(m, m1);
        s = s * fexp2(m - M) + s1 * fexp2(m1 - M);
        m = M;
        m1 = __shfl_xor(m, 32); s1 = __shfl_xor(s, 32);
        M = fmaxf(m, m1);
        s = s * fexp2(m - M) + s1 * fexp2(m1 - M);
        if (lg == 0) {
            size_t idx = (size_t)bx * N + row0 + rf * 16 + l15;
            pm[idx] = M;
            ps[idx] = s;
        }
    }
}

// K2: per-row combine of CB partials -> lse (log2 domain); exact label logit; loss.
__global__ void finalize_kernel(const float* __restrict__ pm, const float* __restrict__ ps,
                                const float* __restrict__ xf, const float* __restrict__ lut,
                                const int* __restrict__ label, float* __restrict__ out_loss,
                                int CB, int N, int P) {
    int row = blockIdx.x, tid = threadIdx.x;
    int y = label[row];
    if (y >= P) return;   // unlabeled -> ce contribution 0
    __shared__ float sm[256], ss[256], sd[256];
    __shared__ int snz[256];
    float m = -1e30f, s = 0.f;
    for (int cb = tid; cb < CB; cb += 256) {
        float bm = pm[(size_t)cb * N + row];
        float bs = ps[(size_t)cb * N + row];
        float M = fmaxf(m, bm);
        s = s * fexp2(m - M) + bs * fexp2(bm - M);
        m = M;
    }
    float lv = lut[(size_t)y * DD + tid];
    sm[tid] = m; ss[tid] = s;
    sd[tid] = xf[(size_t)row * DD + tid] * lv;
    snz[tid] = (lv != 0.f) ? 1 : 0;
    __syncthreads();
    for (int h = 128; h > 0; h >>= 1) {
        if (tid < h) {
            float m2 = sm[tid + h], s2 = ss[tid + h];
            float M = fmaxf(sm[tid], m2);
            ss[tid] = ss[tid] * fexp2(sm[tid] - M) + s2 * fexp2(m2 - M);
            sm[tid] = M;
            sd[tid] += sd[tid + h];
            snz[tid] |= snz[tid + h];
        }
        __syncthreads();
    }
    if (tid == 0) {
        bool bad = (snz[0] == 0);          // own prototype empty -> logit forced to +30
        float lse = LN2 * (sm[0] + log2f(ss[0]));
        float llab = bad ? SCALAR : SCALAR * sd[0];
        atomicAdd(out_loss, (lse - llab) / (float)N);
    }
}

// K3: memory-bank update. One wave per sample; wave-parallel ballot scans.
__global__ __launch_bounds__(64) void update_kernel(
    const float* __restrict__ xf, const int* __restrict__ label,
    const float* __restrict__ ious, const float* __restrict__ lut,
    const int* __restrict__ header, float* __restrict__ out_lut,
    float* __restrict__ out_cq, int N, int P, int Q) {
    extern __shared__ char smem[];
    int* slab = (int*)smem;
    float* siou = (float*)(smem + sizeof(int) * (size_t)N);
    int i = blockIdx.x, lane = threadIdx.x;
    for (int j = lane; j < N; j += 64) { slab[j] = label[j]; siou[j] = ious[j]; }
    __syncthreads();

    float s = 0.f;
    for (int j = lane; j < N; j += 64) s += siou[j];
    #pragma unroll
    for (int off = 32; off > 0; off >>= 1) s += __shfl_xor(s, off);
    if (s >= 0.2f * (float)N) return;   // ious.mean() >= 0.2 -> no update

    int y = slab[i];
    if (y < P) {
        unsigned long long m[16];
        #pragma unroll
        for (int c = 0; c < 16; ++c) {
            int j = c * 64 + lane;
            m[c] = __ballot(j < N && slab[j] == y);
        }
        int first = -1;
        #pragma unroll
        for (int c = 0; c < 16; ++c)
            if (first < 0 && m[c] != 0ull) first = c * 64 + (int)__builtin_ctzll(m[c]);
        if (first != i) return;   // only the first occurrence drives this label

        float4 r = *(const float4*)(lut + (size_t)y * DD + lane * 4);
        for (int pass = 0; pass < 2; ++pass) {
            #pragma unroll
            for (int c = 0; c < 16; ++c) {
                unsigned long long mm = m[c];
                while (mm) {
                    int j = c * 64 + (int)__builtin_ctzll(mm);
                    mm &= mm - 1;
                    float b = (pass == 0) ? 0.5f : siou[j];
                    float a = 1.f - b;
                    float4 xj = *(const float4*)(xf + (size_t)j * DD + lane * 4);
                    r.x = a * r.x + b * xj.x;
                    r.y = a * r.y + b * xj.y;
                    r.z = a * r.z + b * xj.z;
                    r.w = a * r.w + b * xj.w;
                    float ss2 = r.x * r.x + r.y * r.y + r.z * r.z + r.w * r.w;
                    #pragma unroll
                    for (int off = 32; off > 0; off >>= 1) ss2 += __shfl_xor(ss2, off);
                    float inv = 1.f / fmaxf(sqrtf(ss2), 1e-12f);
                    r.x *= inv; r.y *= inv; r.z *= inv; r.w *= inv;
                }
            }
        }
        float* dst = out_lut + (size_t)y * DD + lane * 4;
        dst[0] = r.x; dst[1] = r.y; dst[2] = r.z; dst[3] = r.w;
    } else {
        int rank = 0, U = 0;
        #pragma unroll
        for (int c = 0; c < 16; ++c) {
            int j = c * 64 + lane;
            unsigned long long u = __ballot(j < N && slab[j] >= P);
            U += __popcll(u);
            int base = c * 64;
            if (base + 64 <= i)      rank += __popcll(u);
            else if (base < i)       rank += __popcll(u & ((1ull << (i - base)) - 1ull));
        }
        int h0 = header[0];
        float4 xi = *(const float4*)(xf + (size_t)i * DD + lane * 4);
        long long p1 = ((long long)h0 + rank) % Q;
        long long p2 = ((long long)h0 + U + rank) % Q;
        float* d1 = out_cq + (size_t)p1 * DD + lane * 4;
        float* d2 = out_cq + (size_t)p2 * DD + lane * 4;
        d1[0] = xi.x; d1[1] = xi.y; d1[2] = xi.z; d1[3] = xi.w;
        d2[0] = xi.x; d2[1] = xi.y; d2[2] = xi.z; d2[3] = xi.w;
    }
}

extern "C" void kernel_launch(void* const* d_in, const int* in_sizes, int n_in,
                              void* d_out, int out_size, void* d_ws, size_t ws_size,
                              hipStream_t stream) {
    const float* inputs = (const float*)d_in[0];
    const int* label    = (const int*)d_in[1];
    const float* ious   = (const float*)d_in[2];
    const float* lut    = (const float*)d_in[3];
    const float* cq     = (const float*)d_in[4];
    const int* header   = (const int*)d_in[5];
    float* out = (float*)d_out;

    int N = in_sizes[0] / DD;            // 1024
    int P = in_sizes[3] / DD;            // 100000
    int Q = in_sizes[4] / DD;            // 50000
    int C = P + Q;                       // 150000
    int SUB = (C * 8 + 255) / 256;       // 32-col subtiles = ceil(C/32) = 4688
    int GB = (SUB + NT - 1) / NT;        // 293 blocks in x-groups (4688 = 293*16)
    long PD = (long)P * DD;
    long TOT = (long)C * DD;

    // workspace: xf(1MB) | xb(0.5MB) | pm(1.2MB) | ps(1.2MB)
    char* ws = (char*)d_ws;
    float* xf = (float*)ws;
    unsigned short* xb = (unsigned short*)(ws + (size_t)N * DD * 4);
    float* pm = (float*)(ws + (size_t)N * DD * 6);
    float* ps = pm + (size_t)GB * N;

    float* out_loss = out;
    float* out_lut  = out + 1;
    float* out_cq   = out + 1 + (size_t)P * DD;

    hipLaunchKernelGGL(prep_kernel, dim3(N), dim3(256), 0, stream, inputs, xf, xb, out_loss);
    hipLaunchKernelGGL(gemm_lse_copy_kernel, dim3(4, GB), dim3(256), 0, stream,
                       xb, lut, cq, out, pm, ps, N, PD, TOT, GB);
    hipLaunchKernelGGL(finalize_kernel, dim3(N), dim3(256), 0, stream,
                       pm, ps, xf, lut, label, out_loss, GB, N, P);
    hipLaunchKernelGGL(update_kernel, dim3(N), dim3(64), (size_t)N * 8, stream,
                       xf, label, ious, lut, header, out_lut, out_cq, N, P, Q);
}

// Round 15
// 191.728 us; speedup vs baseline: 1.1251x; 1.1251x over previous
//
#include <hip/hip_runtime.h>
#include <hip/hip_bf16.h>

#define DD 256
#define SCALAR 30.0f
#define K2 43.28085122666891f     // 30 * log2(e)
#define LN2 0.6931471805599453f
#define NT 8                      // column-tiles (64 cols) per gemm block; 2344 = 293*8

typedef __attribute__((ext_vector_type(8))) short bf16x8;
typedef __attribute__((ext_vector_type(4))) float f32x4;

__device__ __forceinline__ float fexp2(float x) {
#if __has_builtin(__builtin_amdgcn_exp2f)
    return __builtin_amdgcn_exp2f(x);
#else
    return exp2f(x);
#endif
}

// RNE float->bf16 (no-NaN inputs)
__device__ __forceinline__ unsigned short f2b(float f) {
    unsigned int u = __builtin_bit_cast(unsigned int, f);
    u += 0x7FFFu + ((u >> 16) & 1u);
    return (unsigned short)(u >> 16);
}

// async global->LDS, 16B per lane; LDS dest is wave-uniform base + lane*16
__device__ __forceinline__ void gload16(const void* g, void* l) {
    __builtin_amdgcn_global_load_lds((const __attribute__((address_space(1))) void*)g,
                                     (__attribute__((address_space(3))) void*)l, 16, 0, 0);
}

// K1: blocks [0,N): prep (x=l2norm, xf/xb, zero loss).
//     blocks [N, N+2048): bt bf16 tile-image build (R13-proven layout).
// bt tile t (32KB): col c (0..63) row of 512B, 16B slots XOR-swizzled slot^=(c&7).
__global__ __launch_bounds__(256) void prep_bt_kernel(
    const float* __restrict__ in, float* __restrict__ xf, unsigned short* __restrict__ xb,
    const float* __restrict__ lut, const float* __restrict__ cq,
    float* __restrict__ out, unsigned short* __restrict__ bt,
    long PD, int C, int CT, int N) {
    __shared__ float red[256];
    int tid = threadIdx.x;
    if ((int)blockIdx.x < N) {
        int row = blockIdx.x;
        float v = in[(size_t)row * DD + tid];
        red[tid] = v * v;
        __syncthreads();
        for (int h = 128; h > 0; h >>= 1) {
            if (tid < h) red[tid] += red[tid + h];
            __syncthreads();
        }
        float nrm = fmaxf(sqrtf(red[0]), 1e-12f);
        float xn = v / nrm;
        xf[(size_t)row * DD + tid] = xn;
        xb[(size_t)row * DD + tid] = f2b(xn);
        if (row == 0 && tid == 0) out[0] = 0.f;
        return;
    }
    int lane = tid & 63;
    int wid = ((blockIdx.x - N) * blockDim.x + tid) >> 6;
    int nw = (2048 * 256) >> 6;
    for (int gc = wid; gc < CT; gc += nw) {
        int t = gc >> 6, c = gc & 63;
        char* tbase = (char*)bt + (size_t)t * 32768;
        long toff = (long)c * 512 + (long)((((lane >> 1) ^ (c & 7)) << 4) + (lane & 1) * 8);
        if (gc >= C) {   // phantom columns -> zero (logit 0, negligible in lse)
            *(short4*)(tbase + toff) = make_short4(0, 0, 0, 0);
            continue;
        }
        long s = (long)gc * 256 + lane * 4;
        float4 v = (s < PD) ? *(const float4*)(lut + s) : *(const float4*)(cq + (s - PD));
        short4 b;
        b.x = f2b(v.x); b.y = f2b(v.y); b.z = f2b(v.z); b.w = f2b(v.w);
        *(short4*)(tbase + toff) = b;
    }
}

// K2: co-scheduled dispatch, grid (6, GB):
//   rb 0..3  -> GEMM role (R13-proven kernel verbatim: 4-wave block, 64 rows/wave,
//               A in regs, bt bf16 LDS double-buffer, counted vmcnt(8)).
//   rb 4..5  -> COPY role: this bx's slice of the shifted out-copy (nt stores).
// Interleaved dispatch order (x fastest) -> each CU hosts a mix; the BW-bound
// copy blocks soak HBM while gemm blocks compute (R13 left HBM idle for 60us).
__global__ __launch_bounds__(256, 2) void gemm_copy_kernel(
    const unsigned short* __restrict__ xb, const unsigned short* __restrict__ bt,
    const float* __restrict__ lut, const float* __restrict__ cq,
    float* __restrict__ dout, float* __restrict__ pm, float* __restrict__ ps,
    int N, long PD, long TOT, int GB) {
    __shared__ char Bs[2][32768];
    int tid = threadIdx.x;
    int rb = blockIdx.x, bx = blockIdx.y;

    if (rb >= 4) {
        // ---------- COPY role ----------
        // chunks m: dout[4m..4m+3] <- flat[4m-1..4m+2]; aligned float4 + shfl_up.
        long MMAX = TOT >> 2;
        long M0 = (long)bx * 32768 + (long)(rb - 4) * 16384;
        long M1 = M0 + 16384; if (M1 > MMAX) M1 = MMAX;
        if (bx == 0 && rb == 4 && tid == 0) {
            dout[1] = lut[0]; dout[2] = lut[1]; dout[3] = lut[2];
        }
        if (bx == GB - 1 && rb == 5 && tid == 0)
            dout[TOT] = cq[TOT - 1 - PD];
        for (long m0 = M0; m0 < M1; m0 += 256) {
            long m = m0 + tid;
            float4 v = make_float4(0.f, 0.f, 0.f, 0.f);
            bool ok = (m >= 1 && m < M1);
            if (ok) {
                long s = 4 * m;
                v = (s < PD) ? *(const float4*)(lut + s) : *(const float4*)(cq + (s - PD));
            }
            float pw = __shfl_up(v.w, 1);
            if ((tid & 63) == 0 && ok) {
                long f = 4 * m - 1;
                pw = (f < PD) ? lut[f] : cq[f - PD];
            }
            if (ok) {
                f32x4 o = (f32x4){pw, v.x, v.y, v.z};
                __builtin_nontemporal_store(o, (f32x4*)(dout + 4 * m));
            }
        }
        return;
    }

    // ---------- GEMM role (R13 verbatim) ----------
    int w = tid >> 6, lane = tid & 63;
    int l15 = lane & 15, lg = lane >> 4;
    int row0 = rb * 256 + w * 64;
    int xr = l15 & 7;

    const char* gt = (const char*)bt + (size_t)bx * NT * 32768;

    // A -> registers FIRST (oldest in vmcnt order): 4 rf x 8 kc x 16B
    bf16x8 areg[4][8];
    const char* ab = (const char*)xb + ((size_t)(row0 + l15) * 256 + lg * 8) * 2;
    #pragma unroll
    for (int rf = 0; rf < 4; ++rf)
        #pragma unroll
        for (int kc = 0; kc < 8; ++kc)
            areg[rf][kc] = *(const bf16x8*)(ab + rf * (16 * 512) + kc * 64);

    // then DMA tiles 0 and 1 (newest 16 vmem ops; 8KB per wave per tile)
    {
        const char* src = gt + w * 8192 + lane * 16;
        #pragma unroll
        for (int i = 0; i < 8; ++i)
            gload16(src + i * 1024, &Bs[0][w * 8192 + i * 1024]);
        #pragma unroll
        for (int i = 0; i < 8; ++i)
            gload16(src + 32768 + i * 1024, &Bs[1][w * 8192 + i * 1024]);
    }

    float rm[4], rs[4];
    #pragma unroll
    for (int rf = 0; rf < 4; ++rf) { rm[rf] = -1e30f; rs[rf] = 0.f; }

    #pragma unroll 1
    for (int st = 0; st < NT; ++st) {
        if (st < NT - 1) asm volatile("s_waitcnt vmcnt(8)" ::: "memory");
        else             asm volatile("s_waitcnt vmcnt(0)" ::: "memory");
        __builtin_amdgcn_s_barrier();

        const char* bufc = &Bs[st & 1][0];
        f32x4 acc[4][4];   // [cf][rf]
        #pragma unroll
        for (int cf = 0; cf < 4; ++cf)
            #pragma unroll
            for (int rf = 0; rf < 4; ++rf) acc[cf][rf] = (f32x4){0.f, 0.f, 0.f, 0.f};

        #pragma unroll
        for (int k0 = 0; k0 < 8; ++k0) {
            int sl = (((k0 * 4 + lg) ^ xr) << 4);
            bf16x8 b[4];
            #pragma unroll
            for (int cf = 0; cf < 4; ++cf)
                b[cf] = *(const bf16x8*)(bufc + (cf * 16 + l15) * 512 + sl);
            #pragma unroll
            for (int rf = 0; rf < 4; ++rf)
                #pragma unroll
                for (int cf = 0; cf < 4; ++cf)
                    acc[cf][rf] = __builtin_amdgcn_mfma_f32_16x16x32_bf16(b[cf], areg[rf][k0], acc[cf][rf], 0, 0, 0);
        }

        __builtin_amdgcn_s_barrier();
        if (st + 2 < NT) {
            const char* src = gt + (st + 2) * 32768 + w * 8192 + lane * 16;
            char* dst = &Bs[st & 1][w * 8192];
            #pragma unroll
            for (int i = 0; i < 8; ++i)
                gload16(src + i * 1024, dst + i * 1024);
        }

        // per-lane fold under the DMA flight
        #pragma unroll
        for (int rf = 0; rf < 4; ++rf) {
            float lmraw = acc[0][rf][0];
            #pragma unroll
            for (int cf = 0; cf < 4; ++cf)
                #pragma unroll
                for (int r = 0; r < 4; ++r)
                    if (cf | r) lmraw = fmaxf(lmraw, acc[cf][rf][r]);
            float lm = fmaxf(rm[rf], K2 * lmraw);
            float ls0 = rs[rf] * fexp2(rm[rf] - lm);
            float ls1 = 0.f;
            #pragma unroll
            for (int cf = 0; cf < 4; ++cf)
                #pragma unroll
                for (int r = 0; r < 4; ++r) {
                    float e = fexp2(fmaf(K2, acc[cf][rf][r], -lm));
                    if (cf & 1) ls1 += e; else ls0 += e;
                }
            rm[rf] = lm; rs[rf] = ls0 + ls1;
        }
    }

    // cross-lane-group merge (copies at lanes l15+16k)
    #pragma unroll
    for (int rf = 0; rf < 4; ++rf) {
        float m = rm[rf], s = rs[rf];
        float m1 = __shfl_xor(m, 16), s1 = __shfl_xor(s, 16);
        float M = fmaxf(m, m1);
        s = s * fexp2(m - M) + s1 * fexp2(m1 - M);
        m = M;
        m1 = __shfl_xor(m, 32); s1 = __shfl_xor(s, 32);
        M = fmaxf(m, m1);
        s = s * fexp2(m - M) + s1 * fexp2(m1 - M);
        if (lg == 0) {
            size_t idx = (size_t)bx * N + row0 + rf * 16 + l15;
            pm[idx] = M;
            ps[idx] = s;
        }
    }
}

// K3: per-row combine of CB partials -> lse (log2 domain); exact label logit; loss.
__global__ void finalize_kernel(const float* __restrict__ pm, const float* __restrict__ ps,
                                const float* __restrict__ xf, const float* __restrict__ lut,
                                const int* __restrict__ label, float* __restrict__ out_loss,
                                int CB, int N, int P) {
    int row = blockIdx.x, tid = threadIdx.x;
    int y = label[row];
    if (y >= P) return;   // unlabeled -> ce contribution 0
    __shared__ float sm[256], ss[256], sd[256];
    __shared__ int snz[256];
    float m = -1e30f, s = 0.f;
    for (int cb = tid; cb < CB; cb += 256) {
        float bm = pm[(size_t)cb * N + row];
        float bs = ps[(size_t)cb * N + row];
        float M = fmaxf(m, bm);
        s = s * fexp2(m - M) + bs * fexp2(bm - M);
        m = M;
    }
    float lv = lut[(size_t)y * DD + tid];
    sm[tid] = m; ss[tid] = s;
    sd[tid] = xf[(size_t)row * DD + tid] * lv;
    snz[tid] = (lv != 0.f) ? 1 : 0;
    __syncthreads();
    for (int h = 128; h > 0; h >>= 1) {
        if (tid < h) {
            float m2 = sm[tid + h], s2 = ss[tid + h];
            float M = fmaxf(sm[tid], m2);
            ss[tid] = ss[tid] * fexp2(sm[tid] - M) + s2 * fexp2(m2 - M);
            sm[tid] = M;
            sd[tid] += sd[tid + h];
            snz[tid] |= snz[tid + h];
        }
        __syncthreads();
    }
    if (tid == 0) {
        bool bad = (snz[0] == 0);          // own prototype empty -> logit forced to +30
        float lse = LN2 * (sm[0] + log2f(ss[0]));
        float llab = bad ? SCALAR : SCALAR * sd[0];
        atomicAdd(out_loss, (lse - llab) / (float)N);
    }
}

// K4: memory-bank update. One wave per sample; wave-parallel ballot scans.
__global__ __launch_bounds__(64) void update_kernel(
    const float* __restrict__ xf, const int* __restrict__ label,
    const float* __restrict__ ious, const float* __restrict__ lut,
    const int* __restrict__ header, float* __restrict__ out_lut,
    float* __restrict__ out_cq, int N, int P, int Q) {
    extern __shared__ char smem[];
    int* slab = (int*)smem;
    float* siou = (float*)(smem + sizeof(int) * (size_t)N);
    int i = blockIdx.x, lane = threadIdx.x;
    for (int j = lane; j < N; j += 64) { slab[j] = label[j]; siou[j] = ious[j]; }
    __syncthreads();

    float s = 0.f;
    for (int j = lane; j < N; j += 64) s += siou[j];
    #pragma unroll
    for (int off = 32; off > 0; off >>= 1) s += __shfl_xor(s, off);
    if (s >= 0.2f * (float)N) return;   // ious.mean() >= 0.2 -> no update

    int y = slab[i];
    if (y < P) {
        unsigned long long m[16];
        #pragma unroll
        for (int c = 0; c < 16; ++c) {
            int j = c * 64 + lane;
            m[c] = __ballot(j < N && slab[j] == y);
        }
        int first = -1;
        #pragma unroll
        for (int c = 0; c < 16; ++c)
            if (first < 0 && m[c] != 0ull) first = c * 64 + (int)__builtin_ctzll(m[c]);
        if (first != i) return;   // only the first occurrence drives this label

        float4 r = *(const float4*)(lut + (size_t)y * DD + lane * 4);
        for (int pass = 0; pass < 2; ++pass) {
            #pragma unroll
            for (int c = 0; c < 16; ++c) {
                unsigned long long mm = m[c];
                while (mm) {
                    int j = c * 64 + (int)__builtin_ctzll(mm);
                    mm &= mm - 1;
                    float b = (pass == 0) ? 0.5f : siou[j];
                    float a = 1.f - b;
                    float4 xj = *(const float4*)(xf + (size_t)j * DD + lane * 4);
                    r.x = a * r.x + b * xj.x;
                    r.y = a * r.y + b * xj.y;
                    r.z = a * r.z + b * xj.z;
                    r.w = a * r.w + b * xj.w;
                    float ss2 = r.x * r.x + r.y * r.y + r.z * r.z + r.w * r.w;
                    #pragma unroll
                    for (int off = 32; off > 0; off >>= 1) ss2 += __shfl_xor(ss2, off);
                    float inv = 1.f / fmaxf(sqrtf(ss2), 1e-12f);
                    r.x *= inv; r.y *= inv; r.z *= inv; r.w *= inv;
                }
            }
        }
        float* dst = out_lut + (size_t)y * DD + lane * 4;
        dst[0] = r.x; dst[1] = r.y; dst[2] = r.z; dst[3] = r.w;
    } else {
        int rank = 0, U = 0;
        #pragma unroll
        for (int c = 0; c < 16; ++c) {
            int j = c * 64 + lane;
            unsigned long long u = __ballot(j < N && slab[j] >= P);
            U += __popcll(u);
            int base = c * 64;
            if (base + 64 <= i)      rank += __popcll(u);
            else if (base < i)       rank += __popcll(u & ((1ull << (i - base)) - 1ull));
        }
        int h0 = header[0];
        float4 xi = *(const float4*)(xf + (size_t)i * DD + lane * 4);
        long long p1 = ((long long)h0 + rank) % Q;
        long long p2 = ((long long)h0 + U + rank) % Q;
        float* d1 = out_cq + (size_t)p1 * DD + lane * 4;
        float* d2 = out_cq + (size_t)p2 * DD + lane * 4;
        d1[0] = xi.x; d1[1] = xi.y; d1[2] = xi.z; d1[3] = xi.w;
        d2[0] = xi.x; d2[1] = xi.y; d2[2] = xi.z; d2[3] = xi.w;
    }
}

extern "C" void kernel_launch(void* const* d_in, const int* in_sizes, int n_in,
                              void* d_out, int out_size, void* d_ws, size_t ws_size,
                              hipStream_t stream) {
    const float* inputs = (const float*)d_in[0];
    const int* label    = (const int*)d_in[1];
    const float* ious   = (const float*)d_in[2];
    const float* lut    = (const float*)d_in[3];
    const float* cq     = (const float*)d_in[4];
    const int* header   = (const int*)d_in[5];
    float* out = (float*)d_out;

    int N = in_sizes[0] / DD;            // 1024
    int P = in_sizes[3] / DD;            // 100000
    int Q = in_sizes[4] / DD;            // 50000
    int C = P + Q;                       // 150000
    int TILES = (C + 63) / 64;           // 2344
    int GB = (TILES + NT - 1) / NT;      // 293 column-groups (2344 = 293*8 exact)
    int CT = TILES * 64;                 // 150016 padded columns
    long PD = (long)P * DD;
    long TOT = (long)C * DD;

    // workspace: xf(1MB) | xb(0.5MB) | pm(1.2MB) | ps(1.2MB) | bt(76.9MB)
    char* ws = (char*)d_ws;
    float* xf = (float*)ws;
    unsigned short* xb = (unsigned short*)(ws + (size_t)N * DD * 4);
    float* pm = (float*)(ws + (size_t)N * DD * 6);
    float* ps = pm + (size_t)GB * N;
    unsigned short* bt = (unsigned short*)((char*)(ps + (size_t)GB * N));

    float* out_loss = out;
    float* out_lut  = out + 1;
    float* out_cq   = out + 1 + (size_t)P * DD;

    hipLaunchKernelGGL(prep_bt_kernel, dim3(N + 2048), dim3(256), 0, stream,
                       inputs, xf, xb, lut, cq, out, bt, PD, C, CT, N);
    hipLaunchKernelGGL(gemm_copy_kernel, dim3(6, GB), dim3(256), 0, stream,
                       xb, bt, lut, cq, out, pm, ps, N, PD, TOT, GB);
    hipLaunchKernelGGL(finalize_kernel, dim3(N), dim3(256), 0, stream,
                       pm, ps, xf, lut, label, out_loss, GB, N, P);
    hipLaunchKernelGGL(update_kernel, dim3(N), dim3(64), (size_t)N * 8, stream,
                       xf, label, ious, lut, header, out_lut, out_cq, N, P, Q);
}